// Round 13
// baseline (459.220 us; speedup 1.0000x reference)
//
#include <hip/hip_runtime.h>

// ---------------------------------------------------------------------------
// Sparse voxel encoder, fp32 dense pipeline.
// d_out = [out2 (24^3*64) | out1 (24^3*64) | out0 (48^3*32)]
// R11 (resubmitted; R12 bench failed at GPU acquisition, never measured):
// conv1 gets VP2 (2 voxels/thread, tile 4x4x8): same 8 weight-float4
// s_loads per (tap,c4) chain now feed 64 FMAs (was 32) -> stall ratio halved.
// ---------------------------------------------------------------------------

constexpr int D0 = 96;

// ---------------- scatter: coords/feats -> dense grid + occupancy ----------
__global__ void scatter_kernel(const int* __restrict__ coords,
                               const float* __restrict__ feats,
                               float* __restrict__ x, float* __restrict__ occ,
                               int N) {
    int n = blockIdx.x * blockDim.x + threadIdx.x;
    if (n >= N) return;
    int i = coords[n * 3 + 0], j = coords[n * 3 + 1], k = coords[n * 3 + 2];
    int flat = (i * D0 + j) * D0 + k;
    const float4* f4 = reinterpret_cast<const float4*>(feats + (size_t)n * 8);
    float4 a = f4[0], b = f4[1];
    float* dst = x + (size_t)flat * 8;
    atomicAdd(dst + 0, a.x); atomicAdd(dst + 1, a.y);
    atomicAdd(dst + 2, a.z); atomicAdd(dst + 3, a.w);
    atomicAdd(dst + 4, b.x); atomicAdd(dst + 5, b.y);
    atomicAdd(dst + 6, b.z); atomicAdd(dst + 7, b.w);
    occ[flat] = 1.0f;
}

// ---------------- 2x2x2 max pool on occupancy ------------------------------
template <int GDO>
__global__ void pool_kernel(const float* __restrict__ occ_in,
                            float* __restrict__ occ_out) {
    int idx = blockIdx.x * blockDim.x + threadIdx.x;
    if (idx >= GDO * GDO * GDO) return;
    int x = idx % GDO, y = (idx / GDO) % GDO, z = idx / (GDO * GDO);
    constexpr int GDI = GDO * 2;
    float m = 0.f;
    #pragma unroll
    for (int dz = 0; dz < 2; dz++)
        #pragma unroll
        for (int dy = 0; dy < 2; dy++)
            #pragma unroll
            for (int dx = 0; dx < 2; dx++)
                m = fmaxf(m, occ_in[((z * 2 + dz) * GDI + y * 2 + dy) * GDI + x * 2 + dx]);
    occ_out[idx] = m;
}

// ---------------- weight repack -------------------------------------------
// dst[i]: i = (((tap*CIN4 + c4)*COUT4 + o4)*4 + r)*4 + c
//   == W[(tap*CIN + c4*4+r)*COUT + o4*4+c]
__device__ inline void repack_one(const float* __restrict__ W,
                                  float* __restrict__ WR, int i, int CIN, int COUT) {
    int c = i & 3;
    int r = (i >> 2) & 3;
    int blk = i >> 4;
    int COUT4 = COUT >> 2, CIN4 = CIN >> 2;
    int o4 = blk % COUT4;
    int c4 = (blk / COUT4) % CIN4;
    int tap = blk / (COUT4 * CIN4);
    WR[i] = W[((size_t)tap * CIN + c4 * 4 + r) * COUT + o4 * 4 + c];
}

constexpr int WR_W0 = 0;              // 27*8*16    = 3456
constexpr int WR_WD0 = 3456;          // 8*16*32    = 4096
constexpr int WR_W1 = 7552;           // 27*32*32   = 27648
constexpr int WR_WD1 = 35200;         // 8*32*64    = 16384
constexpr int WR_W2 = 51584;          // 27*64*64   = 110592
constexpr int WR_TOT = 162176;

__global__ void repack_all_kernel(const float* __restrict__ W0,
                                  const float* __restrict__ Wd0,
                                  const float* __restrict__ W1,
                                  const float* __restrict__ Wd1,
                                  const float* __restrict__ W2,
                                  float* __restrict__ WR) {
    int i = blockIdx.x * 256 + threadIdx.x;
    if (i < WR_WD0)          repack_one(W0,  WR + WR_W0,  i - WR_W0,  8, 16);
    else if (i < WR_W1)      repack_one(Wd0, WR + WR_WD0, i - WR_WD0, 16, 32);
    else if (i < WR_WD1)     repack_one(W1,  WR + WR_W1,  i - WR_W1,  32, 32);
    else if (i < WR_W2)      repack_one(Wd1, WR + WR_WD1, i - WR_WD1, 32, 64);
    else if (i < WR_TOT)     repack_one(W2,  WR + WR_W2,  i - WR_W2,  64, 64);
}

#define FMA4(av, rv, accv)                 \
    accv.x = fmaf(av, rv.x, accv.x);       \
    accv.y = fmaf(av, rv.y, accv.y);       \
    accv.z = fmaf(av, rv.z, accv.z);       \
    accv.w = fmaf(av, rv.w, accv.w);

// ---------------- 3x3x3 SAME conv, relu, occupancy mask --------------------
// VP2: each thread computes voxels (tx,ty,tz) and (tx,ty,tz+4) of a TX x TY x TZ
// tile (TZ = 8): the weight s_load chain per (tap,c4) feeds 2x the FMAs.
template <int CIN, int COUT, int GD, int TX, int TY, int TZ, int CC, int COSPLIT,
          bool REMAP, bool KXU, bool VP2>
__global__ __launch_bounds__(256) void conv3_kernel(
    const float* __restrict__ in, const float* __restrict__ WR,
    const float* __restrict__ bias, const float* __restrict__ occ,
    float* __restrict__ out) {
    constexpr int HX = TX + 2, HY = TY + 2, HZ = TZ + 2;
    constexpr int NV = HX * HY * HZ;
    constexpr int Q = CC / 4;
    constexpr int PADV = 8 / Q;
    constexpr int NVp = NV + PADV;
    constexpr int VOX = TX * TY * TZ / (VP2 ? 2 : 1);  // threads per cout-group
    constexpr int NG = 256 / VOX;
    constexpr int CO_PER = COUT / COSPLIT / NG;
    constexpr int NCH = CIN / CC;
    constexpr int CIN4 = CIN / 4, COUT4 = COUT / 4;
    constexpr int NP = VP2 ? 2 : 1;
    __shared__ float4 lds4[Q * NVp];

    const int t = threadIdx.x;
    constexpr int NBX = GD / TX;
    const int cs = blockIdx.x / NBX;
    const int bx = blockIdx.x % NBX;
    const int x0 = bx * TX, y0 = blockIdx.y * TY, z0 = blockIdx.z * TZ;
    const int v = t & (VOX - 1);
    const int g = t / VOX;  // wave-uniform (VOX >= 64)
    int tx, ty, tz;
    if (REMAP) {  // VOX==64: 4x4x4 footprint (VP2 adds +4 in z)
        tx = v & 3;
        ty = (v >> 3) & 3;
        tz = ((v >> 2) & 1) | (((v >> 5) & 1) << 1);
    } else {
        tx = v % TX;
        ty = (v / TX) % TY;
        tz = v / (TX * TY);
    }
    const int co_base = __builtin_amdgcn_readfirstlane((cs * NG + g) * CO_PER);
    const int co4b = co_base >> 2;
    const float4* wr4 = reinterpret_cast<const float4*>(WR);

    float4 acc4[NP][CO_PER / 4];
    #pragma unroll
    for (int p = 0; p < NP; p++)
        #pragma unroll
        for (int i = 0; i < CO_PER / 4; i++) acc4[p][i] = make_float4(0.f, 0.f, 0.f, 0.f);

    for (int ch = 0; ch < NCH; ++ch) {
        // ---- stage halo tile ----
        constexpr int T4 = NV * Q;
        for (int idx = t; idx < T4; idx += 256) {
            int c4 = idx & (Q - 1);
            int vox = idx / Q;
            int hx = vox % HX, hy = (vox / HX) % HY, hz = vox / (HX * HY);
            int gx = x0 + hx - 1, gy = y0 + hy - 1, gz = z0 + hz - 1;
            float4 val = make_float4(0.f, 0.f, 0.f, 0.f);
            if (gx >= 0 && gx < GD && gy >= 0 && gy < GD && gz >= 0 && gz < GD) {
                val = *reinterpret_cast<const float4*>(
                    in + (size_t)((gz * GD + gy) * GD + gx) * CIN + ch * CC + c4 * 4);
            }
            lds4[c4 * NVp + vox] = val;
        }
        __syncthreads();

        auto body = [&](int tap, int vin) {
            #pragma unroll
            for (int c4 = 0; c4 < Q; ++c4) {
                float4 iv = lds4[c4 * NVp + vin];
                float4 iv2;
                if constexpr (VP2) iv2 = lds4[c4 * NVp + vin + 4 * HX * HY];
                const float4* wp =
                    wr4 + ((size_t)(tap * CIN4 + ch * Q + c4) * COUT4) * 4;
                #pragma unroll
                for (int o4 = 0; o4 < CO_PER / 4; ++o4) {
                    const float4* w4 = wp + (co4b + o4) * 4;
                    float4 r0 = w4[0], r1 = w4[1], r2 = w4[2], r3 = w4[3];
                    FMA4(iv.x, r0, acc4[0][o4]);
                    FMA4(iv.y, r1, acc4[0][o4]);
                    FMA4(iv.z, r2, acc4[0][o4]);
                    FMA4(iv.w, r3, acc4[0][o4]);
                    if constexpr (VP2) {
                        FMA4(iv2.x, r0, acc4[1][o4]);
                        FMA4(iv2.y, r1, acc4[1][o4]);
                        FMA4(iv2.z, r2, acc4[1][o4]);
                        FMA4(iv2.w, r3, acc4[1][o4]);
                    }
                }
            }
        };

        if constexpr (KXU) {
            #pragma unroll 1
            for (int kz = 0; kz < 3; ++kz) {
                #pragma unroll 1
                for (int ky = 0; ky < 3; ++ky) {
                    const int vrow = (tz + kz) * (HX * HY) + (ty + ky) * HX + tx;
                    #pragma unroll
                    for (int kx = 0; kx < 3; ++kx)
                        body((kz * 3 + ky) * 3 + kx, vrow + kx);
                }
            }
        } else {
            #pragma unroll 1
            for (int kz = 0; kz < 3; ++kz) {
                #pragma unroll 1
                for (int ky = 0; ky < 3; ++ky) {
                    const int vrow = (tz + kz) * (HX * HY) + (ty + ky) * HX + tx;
                    #pragma unroll 1
                    for (int kx = 0; kx < 3; ++kx)
                        body((kz * 3 + ky) * 3 + kx, vrow + kx);
                }
            }
        }
        if (ch + 1 < NCH) __syncthreads();
    }
    // ---- epilogue: bias, relu, occupancy mask ----
    #pragma unroll
    for (int p = 0; p < NP; p++) {
        int oz = z0 + tz + p * 4, oy = y0 + ty, ox = x0 + tx;
        int oflat = (oz * GD + oy) * GD + ox;
        float o = occ[oflat];
        float* op = out + (size_t)oflat * COUT + co_base;
        #pragma unroll
        for (int o4 = 0; o4 < CO_PER / 4; o4++) {
            float4 r;
            r.x = fmaxf(acc4[p][o4].x + bias[co_base + o4 * 4 + 0], 0.f) * o;
            r.y = fmaxf(acc4[p][o4].y + bias[co_base + o4 * 4 + 1], 0.f) * o;
            r.z = fmaxf(acc4[p][o4].z + bias[co_base + o4 * 4 + 2], 0.f) * o;
            r.w = fmaxf(acc4[p][o4].w + bias[co_base + o4 * 4 + 3], 0.f) * o;
            *reinterpret_cast<float4*>(op + o4 * 4) = r;
        }
    }
}

// ---------------- 2x2x2 stride-2 VALID conv, relu, occupancy mask ----------
template <int CIN, int COUT, int GDI, int CC>
__global__ __launch_bounds__(256) void convd_kernel(
    const float* __restrict__ in, const float* __restrict__ WR,
    const float* __restrict__ bias, const float* __restrict__ occ,
    float* __restrict__ out) {
    constexpr int GDO = GDI / 2;
    constexpr int VOX = 64, NG = 4;
    constexpr int CO_PER = COUT / NG;
    constexpr int HX = 8, HY = 8, HZ = 8, NV = HX * HY * HZ;
    constexpr int Q = CC / 4;
    constexpr int NVp = NV + 8 / Q;
    constexpr int NCH = CIN / CC;
    constexpr int CIN4 = CIN / 4, COUT4 = COUT / 4;
    __shared__ float4 lds4[Q * NVp];

    const int t = threadIdx.x;
    const int x0 = blockIdx.x * 4, y0 = blockIdx.y * 4, z0 = blockIdx.z * 4;
    const int v = t & 63;
    const int g = t >> 6;
    const int tx = v % 4, ty = (v / 4) % 4, tz = v / 16;
    const int co_base = __builtin_amdgcn_readfirstlane(g * CO_PER);
    const int co4b = co_base >> 2;
    const float4* wr4 = reinterpret_cast<const float4*>(WR);

    float4 acc4[CO_PER / 4];
    #pragma unroll
    for (int i = 0; i < CO_PER / 4; i++) acc4[i] = make_float4(0.f, 0.f, 0.f, 0.f);

    for (int ch = 0; ch < NCH; ++ch) {
        constexpr int T4 = NV * Q;
        for (int idx = t; idx < T4; idx += 256) {
            int c4 = idx & (Q - 1);
            int vox = idx / Q;
            int hx = vox % HX, hy = (vox / HX) % HY, hz = vox / (HX * HY);
            int gx = x0 * 2 + hx, gy = y0 * 2 + hy, gz = z0 * 2 + hz;
            lds4[c4 * NVp + vox] = *reinterpret_cast<const float4*>(
                in + (size_t)((gz * GDI + gy) * GDI + gx) * CIN + ch * CC + c4 * 4);
        }
        __syncthreads();
        #pragma unroll 1
        for (int kz = 0; kz < 2; ++kz) {
            #pragma unroll
            for (int ky = 0; ky < 2; ++ky) {
                #pragma unroll
                for (int kx = 0; kx < 2; ++kx) {
                    const int tap = kz * 4 + ky * 2 + kx;
                    const int vin = (tz * 2 + kz) * (HX * HY) + (ty * 2 + ky) * HX + (tx * 2 + kx);
                    #pragma unroll
                    for (int c4 = 0; c4 < Q; ++c4) {
                        float4 iv = lds4[c4 * NVp + vin];
                        const float4* wp =
                            wr4 + ((size_t)(tap * CIN4 + ch * Q + c4) * COUT4) * 4;
                        #pragma unroll
                        for (int o4 = 0; o4 < CO_PER / 4; ++o4) {
                            const float4* w4 = wp + (co4b + o4) * 4;
                            float4 r0 = w4[0], r1 = w4[1], r2 = w4[2], r3 = w4[3];
                            FMA4(iv.x, r0, acc4[o4]);
                            FMA4(iv.y, r1, acc4[o4]);
                            FMA4(iv.z, r2, acc4[o4]);
                            FMA4(iv.w, r3, acc4[o4]);
                        }
                    }
                }
            }
        }
        if (ch + 1 < NCH) __syncthreads();
    }
    int oz = z0 + tz, oy = y0 + ty, ox = x0 + tx;
    int oflat = (oz * GDO + oy) * GDO + ox;
    float o = occ[oflat];
    float* op = out + (size_t)oflat * COUT + co_base;
    #pragma unroll
    for (int o4 = 0; o4 < CO_PER / 4; o4++) {
        float4 r;
        r.x = fmaxf(acc4[o4].x + bias[co_base + o4 * 4 + 0], 0.f) * o;
        r.y = fmaxf(acc4[o4].y + bias[co_base + o4 * 4 + 1], 0.f) * o;
        r.z = fmaxf(acc4[o4].z + bias[co_base + o4 * 4 + 2], 0.f) * o;
        r.w = fmaxf(acc4[o4].w + bias[co_base + o4 * 4 + 3], 0.f) * o;
        *reinterpret_cast<float4*>(op + o4 * 4) = r;
    }
}

// ---------------------------------------------------------------------------
extern "C" void kernel_launch(void* const* d_in, const int* in_sizes, int n_in,
                              void* d_out, int out_size, void* d_ws, size_t ws_size,
                              hipStream_t stream) {
    const int* coords = (const int*)d_in[0];
    const float* feats = (const float*)d_in[1];
    const float* W0 = (const float*)d_in[2];
    const float* b0 = (const float*)d_in[3];
    const float* Wd0 = (const float*)d_in[4];
    const float* bd0 = (const float*)d_in[5];
    const float* W1 = (const float*)d_in[6];
    const float* b1 = (const float*)d_in[7];
    const float* Wd1 = (const float*)d_in[8];
    const float* bd1 = (const float*)d_in[9];
    const float* W2 = (const float*)d_in[10];
    const float* b2 = (const float*)d_in[11];
    const int N = in_sizes[0] / 3;

    // workspace layout (floats)
    float* ws = (float*)d_ws;
    float* x = ws;
    float* h1 = ws;  // reuse x region after conv0 consumes it
    float* occ = ws + 7077888;
    float* h = ws + 7962624;
    float* occ0 = ws + 22118400;
    float* occ1 = ws + 22228992;
    float* WR = ws + 23000000;  // repacked weights, 162176 floats

    float* out = (float*)d_out;
    float* out2 = out;            // 24^3*64
    float* out1 = out + 884736;   // 24^3*64
    float* out0 = out + 1769472;  // 48^3*32

    repack_all_kernel<<<(WR_TOT + 255) / 256, 256, 0, stream>>>(W0, Wd0, W1, Wd1, W2, WR);

    hipMemsetAsync(x, 0, (size_t)(7077888 + 884736) * sizeof(float), stream);

    scatter_kernel<<<(N + 255) / 256, 256, 0, stream>>>(coords, feats, x, occ, N);
    pool_kernel<48><<<(110592 + 255) / 256, 256, 0, stream>>>(occ, occ0);
    pool_kernel<24><<<(13824 + 255) / 256, 256, 0, stream>>>(occ0, occ1);

    // conv0: 96^3, 8->16, tile 4x4x4 REMAP, CO_PER=4 (unchanged from R10)
    conv3_kernel<8, 16, 96, 4, 4, 4, 8, 1, true, true, false>
        <<<dim3(24, 24, 24), 256, 0, stream>>>(x, WR + WR_W0, b0, occ, h);
    // convd0: 96->48, 16->32 (unchanged)
    convd_kernel<16, 32, 96, 16>
        <<<dim3(12, 12, 12), 256, 0, stream>>>(h, WR + WR_WD0, bd0, occ0, out0);
    // conv1: 48^3, 32->32, tile 4x4x8 REMAP+VP2, CO_PER=8, 864 blocks, 46.2KB LDS
    conv3_kernel<32, 32, 48, 4, 4, 8, 32, 1, true, true, true>
        <<<dim3(12, 12, 6), 256, 0, stream>>>(out0, WR + WR_W1, b1, occ0, h1);
    // convd1: 48->24, 32->64 (unchanged)
    convd_kernel<32, 64, 48, 16>
        <<<dim3(6, 6, 6), 256, 0, stream>>>(h1, WR + WR_WD1, bd1, occ1, out1);
    // conv2: 24^3, 64->64, tile 4x4x4 REMAP, COSPLIT=4 (unchanged from R10)
    conv3_kernel<64, 64, 24, 4, 4, 4, 32, 4, true, true, false>
        <<<dim3(24, 6, 6), 256, 0, stream>>>(out1, WR + WR_W2, b2, occ1, out2);
}